// Round 7
// baseline (309.282 us; speedup 1.0000x reference)
//
#include <hip/hip_runtime.h>

#define N_NODES 50000
#define N_EDGES 800000
#define N_B 2
#define N_C 64
#define BN_ROWS (N_B * N_NODES)

__device__ inline unsigned short f2bf(float f) {
  unsigned int u = __float_as_uint(f);
  return (unsigned short)((u + 0x7fffu + ((u >> 16) & 1u)) >> 16);  // RNE
}
__device__ inline float bf2f(unsigned short h) { return __uint_as_float(((unsigned int)h) << 16); }
__device__ inline float lof(unsigned int u) { return __uint_as_float(u << 16); }
__device__ inline float hif(unsigned int u) { return __uint_as_float(u & 0xffff0000u); }

// compile-time-folded selectors (used only with unrolled constant kk)
__device__ inline float bsel(uint4 q, int kk) {
  unsigned int w = (kk < 2) ? q.x : (kk < 4) ? q.y : (kk < 6) ? q.z : q.w;
  return (kk & 1) ? hif(w) : lof(w);
}
__device__ inline float fsel(float4 a, float4 b, int kk) {
  float4 s = (kk < 4) ? a : b;
  int m = kk & 3;
  return m == 0 ? s.x : m == 1 ? s.y : m == 2 ? s.z : s.w;
}
__device__ inline void unpk8(uint4 q, float* f) {
  f[0] = lof(q.x); f[1] = hif(q.x); f[2] = lof(q.y); f[3] = hif(q.y);
  f[4] = lof(q.z); f[5] = hif(q.z); f[6] = lof(q.w); f[7] = hif(q.w);
}

// ---------------- degree count (non-self-loop edges per source row) ----------
__global__ __launch_bounds__(256) void k_deg(const int* __restrict__ ei, int* __restrict__ deg) {
  int e = blockIdx.x * 256 + threadIdx.x;
  if (e >= N_EDGES) return;
  int r = ei[e];
  int c = ei[N_EDGES + e];
  if (r != c) atomicAdd(&deg[r], 1);
}

// ---------------- segment allocator: per-wave prefix + 1 atomic per wave -----
__global__ __launch_bounds__(256) void k_offsets(const int* __restrict__ deg, int* __restrict__ counter,
                                                 int* __restrict__ rowptr, int* __restrict__ cursor,
                                                 float* __restrict__ dis) {
  int n = blockIdx.x * 256 + threadIdx.x;
  int lane = threadIdx.x & 63;
  int d = (n < N_NODES) ? deg[n] : 0;
  int pre = d;
#pragma unroll
  for (int off = 1; off < 64; off <<= 1) {
    int v = __shfl_up(pre, off);
    if (lane >= off) pre += v;
  }
  int waveTotal = __shfl(pre, 63);
  int wbase = 0;
  if (lane == 63) wbase = atomicAdd(counter, waveTotal);
  wbase = __shfl(wbase, 63);
  if (n < N_NODES) {
    int off0 = wbase + pre - d;
    rowptr[n] = off0;
    cursor[n] = off0;
    dis[n] = d > 0 ? rsqrtf((float)d) : 0.0f;
  }
}

// ---------------- fill CSR: packed (col, lap) int2, one 8B scatter/edge ------
__global__ __launch_bounds__(256) void k_fill(const int* __restrict__ ei, const float* __restrict__ ew,
                                              const float* __restrict__ dis, int* __restrict__ cursor,
                                              int2* __restrict__ ccv) {
  int e = blockIdx.x * 256 + threadIdx.x;
  if (e >= N_EDGES) return;
  int r = ei[e];
  int c = ei[N_EDGES + e];
  if (r == c) return;
  float v = -dis[r] * ew[e] * dis[c];
  int pos = atomicAdd(&cursor[r], 1);
  ccv[pos] = make_int2(c, __float_as_int(v));
}

// ---------------- x (fp32) -> bf16 copy --------------------------------------
__global__ __launch_bounds__(256) void k_cvt(const float* __restrict__ x, unsigned short* __restrict__ xb) {
  int i = blockIdx.x * 256 + threadIdx.x;  // float4-quad index
  if (i >= BN_ROWS * 16) return;
  float4 v = ((const float4*)x)[i];
  ushort4 h;
  h.x = f2bf(v.x); h.y = f2bf(v.y); h.z = f2bf(v.z); h.w = f2bf(v.w);
  ((ushort4*)xb)[i] = h;
}

// ---------------- SPMM: dst[b,n,:] = sum_e lap_e * src[b,col_e,:] ------------
// One wave per NODE, BOTH batches. lane = (edge-slot g = l>>3) x (channel
// group cg = l&7). Per 8 edges: 1 per-lane ccv load + 2 uint4 gathers.
#define UNPK_FMA(Q, A0, A1, A2, A3, A4, A5, A6, A7, V) \
  A0 += (V) * lof(Q.x); A1 += (V) * hif(Q.x); \
  A2 += (V) * lof(Q.y); A3 += (V) * hif(Q.y); \
  A4 += (V) * lof(Q.z); A5 += (V) * hif(Q.z); \
  A6 += (V) * lof(Q.w); A7 += (V) * hif(Q.w);

#define RED3(A) { A += __shfl_xor(A, 8); A += __shfl_xor(A, 16); A += __shfl_xor(A, 32); }

template <int BFOUT>
__global__ __launch_bounds__(256) void k_spmm(const unsigned short* __restrict__ src, void* __restrict__ dstv,
                                              const int* __restrict__ rowptr, const int* __restrict__ deg,
                                              const int2* __restrict__ ccv) {
  int n = (blockIdx.x * 256 + threadIdx.x) >> 6;
  int lane = threadIdx.x & 63;
  if (n >= N_NODES) return;
  const int g = lane >> 3;
  const int cg = lane & 7;
  const unsigned short* s0 = src;
  const unsigned short* s1 = src + (size_t)N_NODES * N_C;
  int r0 = rowptr[n];
  int end = r0 + deg[n];
  float a00 = 0, a01 = 0, a02 = 0, a03 = 0, a04 = 0, a05 = 0, a06 = 0, a07 = 0;
  float a10 = 0, a11 = 0, a12 = 0, a13 = 0, a14 = 0, a15 = 0, a16 = 0, a17 = 0;
#pragma unroll 2
  for (int i = r0; i < end; i += 8) {
    int idx = i + g;
    bool ok = idx < end;
    int2 pe = ccv[ok ? idx : (end - 1)];
    float val = ok ? __int_as_float(pe.y) : 0.0f;
    size_t off = (size_t)pe.x * N_C + cg * 8;  // ushort units; 16B aligned
    uint4 q0 = *(const uint4*)(s0 + off);
    uint4 q1 = *(const uint4*)(s1 + off);
    UNPK_FMA(q0, a00, a01, a02, a03, a04, a05, a06, a07, val)
    UNPK_FMA(q1, a10, a11, a12, a13, a14, a15, a16, a17, val)
  }
  RED3(a00) RED3(a01) RED3(a02) RED3(a03) RED3(a04) RED3(a05) RED3(a06) RED3(a07)
  RED3(a10) RED3(a11) RED3(a12) RED3(a13) RED3(a14) RED3(a15) RED3(a16) RED3(a17)
  if (BFOUT) {
    unsigned short* d = (unsigned short*)dstv;
    if (g == 0) {
      uint4 o;
      o.x = (unsigned)f2bf(a00) | ((unsigned)f2bf(a01) << 16);
      o.y = (unsigned)f2bf(a02) | ((unsigned)f2bf(a03) << 16);
      o.z = (unsigned)f2bf(a04) | ((unsigned)f2bf(a05) << 16);
      o.w = (unsigned)f2bf(a06) | ((unsigned)f2bf(a07) << 16);
      *(uint4*)(d + (size_t)n * N_C + cg * 8) = o;
    } else if (g == 1) {
      uint4 o;
      o.x = (unsigned)f2bf(a10) | ((unsigned)f2bf(a11) << 16);
      o.y = (unsigned)f2bf(a12) | ((unsigned)f2bf(a13) << 16);
      o.z = (unsigned)f2bf(a14) | ((unsigned)f2bf(a15) << 16);
      o.w = (unsigned)f2bf(a16) | ((unsigned)f2bf(a17) << 16);
      *(uint4*)(d + ((size_t)N_NODES + n) * N_C + cg * 8) = o;
    }
  } else {
    float* d = (float*)dstv;
    if (g == 0) {
      *(float4*)(d + (size_t)n * N_C + cg * 8) = make_float4(a00, a01, a02, a03);
      *(float4*)(d + (size_t)n * N_C + cg * 8 + 4) = make_float4(a04, a05, a06, a07);
    } else if (g == 1) {
      *(float4*)(d + ((size_t)N_NODES + n) * N_C + cg * 8) = make_float4(a10, a11, a12, a13);
      *(float4*)(d + ((size_t)N_NODES + n) * N_C + cg * 8 + 4) = make_float4(a14, a15, a16, a17);
    }
  }
}

// ---------------- fused GEMM: out = x@(W0-W2) + Tx1@W1 + Z@(2*W2) + bias -----
// Round-6 diagnosis: 49us latency-bound (occ 13%, 4x 8B loads in flight/wave).
// Fix: 64-row tile (1563 blocks), bf16 weights in 24KB LDS (6 blocks/CU by
// LDS), single interleaved k-loop over all 3 channels with 8 grouped loads
// per k8-step. Z read fp32 in-place from `out` (clamped tail rows stay inside
// the last block's own tile; their products are never stored -> no race).
__global__ __launch_bounds__(256) void k_gemm(const unsigned short* __restrict__ xb,
                                              const unsigned short* __restrict__ t1h,
                                              const float* __restrict__ w,
                                              const float* __restrict__ bias,
                                              float* out) {
  __shared__ unsigned short wl[3 * 4096];  // 24KB combined bf16 weights
  int t = threadIdx.x;
  for (int i = t; i < 4096; i += 256) {
    float w0 = w[i];
    float w1 = w[4096 + i];
    float w2 = w[8192 + i];
    wl[i] = f2bf(w0 - w2);
    wl[4096 + i] = f2bf(w1);
    wl[8192 + i] = f2bf(2.0f * w2);
  }
  __syncthreads();
  const int tx8 = (t & 7) * 8;        // cols tx8 .. tx8+7
  const int rg = t >> 3;              // 0..31 -> 2 rows each; tile = 64 rows
  const size_t base = (size_t)blockIdx.x * 64 + (size_t)rg * 2;
  const size_t rmax = BN_ROWS - 1;
  const size_t r0 = base < rmax ? base : rmax;
  const size_t r1 = base + 1 < rmax ? base + 1 : rmax;
  const unsigned short* xp0 = xb + r0 * 64;
  const unsigned short* xp1 = xb + r1 * 64;
  const unsigned short* tp0 = t1h + r0 * 64;
  const unsigned short* tp1 = t1h + r1 * 64;
  const float* zp0 = out + r0 * 64;
  const float* zp1 = out + r1 * 64;

  float a0[8], a1[8];
  {
    const float4 b0 = *(const float4*)&bias[tx8];
    const float4 b1 = *(const float4*)&bias[tx8 + 4];
    a0[0] = b0.x; a0[1] = b0.y; a0[2] = b0.z; a0[3] = b0.w;
    a0[4] = b1.x; a0[5] = b1.y; a0[6] = b1.z; a0[7] = b1.w;
#pragma unroll
    for (int j = 0; j < 8; ++j) a1[j] = a0[j];
  }

#pragma unroll 2
  for (int k8 = 0; k8 < 64; k8 += 8) {
    // grouped independent loads (16B each) -> MLP
    uint4 x0q = *(const uint4*)(xp0 + k8);
    uint4 x1q = *(const uint4*)(xp1 + k8);
    uint4 t0q = *(const uint4*)(tp0 + k8);
    uint4 t1q = *(const uint4*)(tp1 + k8);
    float4 z00 = *(const float4*)(zp0 + k8);
    float4 z01 = *(const float4*)(zp0 + k8 + 4);
    float4 z10 = *(const float4*)(zp1 + k8);
    float4 z11 = *(const float4*)(zp1 + k8 + 4);
#pragma unroll
    for (int kk = 0; kk < 8; ++kk) {
      const int k = k8 + kk;
      uint4 wq0 = *(const uint4*)&wl[k * 64 + tx8];
      uint4 wq1 = *(const uint4*)&wl[4096 + k * 64 + tx8];
      uint4 wq2 = *(const uint4*)&wl[8192 + k * 64 + tx8];
      float wf0[8], wf1[8], wf2[8];
      unpk8(wq0, wf0);
      unpk8(wq1, wf1);
      unpk8(wq2, wf2);
      const float xv0 = bsel(x0q, kk), xv1 = bsel(x1q, kk);
      const float tv0 = bsel(t0q, kk), tv1 = bsel(t1q, kk);
      const float zv0 = fsel(z00, z01, kk), zv1 = fsel(z10, z11, kk);
#pragma unroll
      for (int j = 0; j < 8; ++j) {
        a0[j] += xv0 * wf0[j];
        a1[j] += xv1 * wf0[j];
        a0[j] += tv0 * wf1[j];
        a1[j] += tv1 * wf1[j];
        a0[j] += zv0 * wf2[j];
        a1[j] += zv1 * wf2[j];
      }
    }
  }

  if (base < BN_ROWS) {
    *(float4*)&out[base * 64 + tx8] = make_float4(a0[0], a0[1], a0[2], a0[3]);
    *(float4*)&out[base * 64 + tx8 + 4] = make_float4(a0[4], a0[5], a0[6], a0[7]);
  }
  if (base + 1 < BN_ROWS) {
    *(float4*)&out[(base + 1) * 64 + tx8] = make_float4(a1[0], a1[1], a1[2], a1[3]);
    *(float4*)&out[(base + 1) * 64 + tx8 + 4] = make_float4(a1[4], a1[5], a1[6], a1[7]);
  }
}

extern "C" void kernel_launch(void* const* d_in, const int* in_sizes, int n_in,
                              void* d_out, int out_size, void* d_ws, size_t ws_size,
                              hipStream_t stream) {
  const float* x = (const float*)d_in[0];
  const int* ei = (const int*)d_in[1];        // [2, E] int32
  const float* ew = (const float*)d_in[2];
  const float* w = (const float*)d_in[3];     // [3,64,64]
  const float* bias = (const float*)d_in[4];  // [64]
  float* out = (float*)d_out;

  // workspace layout (4-byte units)
  int* ws32 = (int*)d_ws;
  const size_t NA = 50048;  // padded N (divisible by 16 -> keeps 16B alignment)
  int* deg = ws32;                          // [0..N) degrees, [N] = counter
  int* counter = deg + N_NODES;
  int* cursor = ws32 + NA;
  float* dis = (float*)(cursor + NA);
  int* rowptr = (int*)(dis + NA);
  int2* ccv = (int2*)(rowptr + NA);                       // 2*E ints
  unsigned short* xb = (unsigned short*)(rowptr + NA + 2 * N_EDGES);   // BN_ROWS*64 bf16
  unsigned short* t1h = xb + (size_t)BN_ROWS * N_C;                    // BN_ROWS*64 bf16
  const size_t NEED = ((size_t)(4 * NA + 2 * N_EDGES) + (size_t)BN_ROWS * N_C) * 4;
  if (ws_size < NEED) return;  // clean fail instead of corruption

  hipMemsetAsync(deg, 0, (N_NODES + 1) * sizeof(int), stream);  // deg + counter
  k_cvt<<<(BN_ROWS * 16 + 255) / 256, 256, 0, stream>>>(x, xb);
  k_deg<<<(N_EDGES + 255) / 256, 256, 0, stream>>>(ei, deg);
  k_offsets<<<(N_NODES + 255) / 256, 256, 0, stream>>>(deg, counter, rowptr, cursor, dis);
  k_fill<<<(N_EDGES + 255) / 256, 256, 0, stream>>>(ei, ew, dis, cursor, ccv);
  // Tx1 = L x   (bf16 out, both batches per wave)
  k_spmm<1><<<(N_NODES * 64 + 255) / 256, 256, 0, stream>>>(xb, t1h, rowptr, deg, ccv);
  // Z = L Tx1   (fp32, into d_out, both batches per wave)
  k_spmm<0><<<(N_NODES * 64 + 255) / 256, 256, 0, stream>>>(t1h, out, rowptr, deg, ccv);
  // out = x@(W0-W2) + Tx1@W1 + Z@(2W2) + bias  (in-place over Z)
  k_gemm<<<(BN_ROWS + 63) / 64, 256, 0, stream>>>(xb, t1h, w, bias, out);
}

// Round 8
// 279.336 us; speedup vs baseline: 1.1072x; 1.1072x over previous
//
#include <hip/hip_runtime.h>

#define N_NODES 50000
#define N_EDGES 800000
#define N_B 2
#define N_C 64
#define BN_ROWS (N_B * N_NODES)

typedef __attribute__((ext_vector_type(8))) short short8;   // 8 bf16 = 4 VGPR
typedef __attribute__((ext_vector_type(4))) float f32x4;    // MFMA accum

__device__ inline unsigned short f2bf(float f) {
  unsigned int u = __float_as_uint(f);
  return (unsigned short)((u + 0x7fffu + ((u >> 16) & 1u)) >> 16);  // RNE
}
__device__ inline float bf2f(unsigned short h) { return __uint_as_float(((unsigned int)h) << 16); }
__device__ inline float lof(unsigned int u) { return __uint_as_float(u << 16); }
__device__ inline float hif(unsigned int u) { return __uint_as_float(u & 0xffff0000u); }

// ---------------- degree count (non-self-loop edges per source row) ----------
__global__ __launch_bounds__(256) void k_deg(const int* __restrict__ ei, int* __restrict__ deg) {
  int e = blockIdx.x * 256 + threadIdx.x;
  if (e >= N_EDGES) return;
  int r = ei[e];
  int c = ei[N_EDGES + e];
  if (r != c) atomicAdd(&deg[r], 1);
}

// ---------------- segment allocator: per-wave prefix + 1 atomic per wave -----
__global__ __launch_bounds__(256) void k_offsets(const int* __restrict__ deg, int* __restrict__ counter,
                                                 int* __restrict__ rowptr, int* __restrict__ cursor,
                                                 float* __restrict__ dis) {
  int n = blockIdx.x * 256 + threadIdx.x;
  int lane = threadIdx.x & 63;
  int d = (n < N_NODES) ? deg[n] : 0;
  int pre = d;
#pragma unroll
  for (int off = 1; off < 64; off <<= 1) {
    int v = __shfl_up(pre, off);
    if (lane >= off) pre += v;
  }
  int waveTotal = __shfl(pre, 63);
  int wbase = 0;
  if (lane == 63) wbase = atomicAdd(counter, waveTotal);
  wbase = __shfl(wbase, 63);
  if (n < N_NODES) {
    int off0 = wbase + pre - d;
    rowptr[n] = off0;
    cursor[n] = off0;
    dis[n] = d > 0 ? rsqrtf((float)d) : 0.0f;
  }
}

// ---------------- fill CSR: packed (col, lap) int2, one 8B scatter/edge ------
__global__ __launch_bounds__(256) void k_fill(const int* __restrict__ ei, const float* __restrict__ ew,
                                              const float* __restrict__ dis, int* __restrict__ cursor,
                                              int2* __restrict__ ccv) {
  int e = blockIdx.x * 256 + threadIdx.x;
  if (e >= N_EDGES) return;
  int r = ei[e];
  int c = ei[N_EDGES + e];
  if (r == c) return;
  float v = -dis[r] * ew[e] * dis[c];
  int pos = atomicAdd(&cursor[r], 1);
  ccv[pos] = make_int2(c, __float_as_int(v));
}

// ---------------- x (fp32) -> bf16 copy --------------------------------------
__global__ __launch_bounds__(256) void k_cvt(const float* __restrict__ x, unsigned short* __restrict__ xb) {
  int i = blockIdx.x * 256 + threadIdx.x;  // float4-quad index
  if (i >= BN_ROWS * 16) return;
  float4 v = ((const float4*)x)[i];
  ushort4 h;
  h.x = f2bf(v.x); h.y = f2bf(v.y); h.z = f2bf(v.z); h.w = f2bf(v.w);
  ((ushort4*)xb)[i] = h;
}

// ---------------- SPMM: dst[b,n,:] = sum_e lap_e * src[b,col_e,:] ------------
// One wave per NODE, BOTH batches. lane = (edge-slot g = l>>3) x (channel
// group cg = l&7). Per 8 edges: 1 per-lane ccv load + 2 uint4 gathers.
#define UNPK_FMA(Q, A0, A1, A2, A3, A4, A5, A6, A7, V) \
  A0 += (V) * lof(Q.x); A1 += (V) * hif(Q.x); \
  A2 += (V) * lof(Q.y); A3 += (V) * hif(Q.y); \
  A4 += (V) * lof(Q.z); A5 += (V) * hif(Q.z); \
  A6 += (V) * lof(Q.w); A7 += (V) * hif(Q.w);

#define RED3(A) { A += __shfl_xor(A, 8); A += __shfl_xor(A, 16); A += __shfl_xor(A, 32); }

template <int BFOUT>
__global__ __launch_bounds__(256) void k_spmm(const unsigned short* __restrict__ src, void* __restrict__ dstv,
                                              const int* __restrict__ rowptr, const int* __restrict__ deg,
                                              const int2* __restrict__ ccv) {
  int n = (blockIdx.x * 256 + threadIdx.x) >> 6;
  int lane = threadIdx.x & 63;
  if (n >= N_NODES) return;
  const int g = lane >> 3;
  const int cg = lane & 7;
  const unsigned short* s0 = src;
  const unsigned short* s1 = src + (size_t)N_NODES * N_C;
  int r0 = rowptr[n];
  int end = r0 + deg[n];
  float a00 = 0, a01 = 0, a02 = 0, a03 = 0, a04 = 0, a05 = 0, a06 = 0, a07 = 0;
  float a10 = 0, a11 = 0, a12 = 0, a13 = 0, a14 = 0, a15 = 0, a16 = 0, a17 = 0;
#pragma unroll 2
  for (int i = r0; i < end; i += 8) {
    int idx = i + g;
    bool ok = idx < end;
    int2 pe = ccv[ok ? idx : (end - 1)];
    float val = ok ? __int_as_float(pe.y) : 0.0f;
    size_t off = (size_t)pe.x * N_C + cg * 8;  // ushort units; 16B aligned
    uint4 q0 = *(const uint4*)(s0 + off);
    uint4 q1 = *(const uint4*)(s1 + off);
    UNPK_FMA(q0, a00, a01, a02, a03, a04, a05, a06, a07, val)
    UNPK_FMA(q1, a10, a11, a12, a13, a14, a15, a16, a17, val)
  }
  RED3(a00) RED3(a01) RED3(a02) RED3(a03) RED3(a04) RED3(a05) RED3(a06) RED3(a07)
  RED3(a10) RED3(a11) RED3(a12) RED3(a13) RED3(a14) RED3(a15) RED3(a16) RED3(a17)
  if (BFOUT) {
    unsigned short* d = (unsigned short*)dstv;
    if (g == 0) {
      uint4 o;
      o.x = (unsigned)f2bf(a00) | ((unsigned)f2bf(a01) << 16);
      o.y = (unsigned)f2bf(a02) | ((unsigned)f2bf(a03) << 16);
      o.z = (unsigned)f2bf(a04) | ((unsigned)f2bf(a05) << 16);
      o.w = (unsigned)f2bf(a06) | ((unsigned)f2bf(a07) << 16);
      *(uint4*)(d + (size_t)n * N_C + cg * 8) = o;
    } else if (g == 1) {
      uint4 o;
      o.x = (unsigned)f2bf(a10) | ((unsigned)f2bf(a11) << 16);
      o.y = (unsigned)f2bf(a12) | ((unsigned)f2bf(a13) << 16);
      o.z = (unsigned)f2bf(a14) | ((unsigned)f2bf(a15) << 16);
      o.w = (unsigned)f2bf(a16) | ((unsigned)f2bf(a17) << 16);
      *(uint4*)(d + ((size_t)N_NODES + n) * N_C + cg * 8) = o;
    }
  } else {
    float* d = (float*)dstv;
    if (g == 0) {
      *(float4*)(d + (size_t)n * N_C + cg * 8) = make_float4(a00, a01, a02, a03);
      *(float4*)(d + (size_t)n * N_C + cg * 8 + 4) = make_float4(a04, a05, a06, a07);
    } else if (g == 1) {
      *(float4*)(d + ((size_t)N_NODES + n) * N_C + cg * 8) = make_float4(a10, a11, a12, a13);
      *(float4*)(d + ((size_t)N_NODES + n) * N_C + cg * 8 + 4) = make_float4(a14, a15, a16, a17);
    }
  }
}

// ---------------- MFMA GEMM: out = [x|Tx1|Z] @ [W0-W2; W1; 2W2] + bias -------
// Round-7 post-mortem: VALU-FMA gemm is latency+VALU bound (77us). MFMA makes
// compute free (~150K MFMAs total) and turns the kernel into streaming loads.
// K=192 = 6 ktiles of 32; B fragments packed bf16 in LDS in fragment order
// (lane l, elem j -> B[(l>>4)*8+j][l&15]); A frags are 16B row loads (x, Tx1
// bf16 direct; Z fp32 -> cvt). C/D: col=lane&15, row=(lane>>4)*4+reg (m89).
// In-place Z: each wave reads ONLY its own 16 rows, then stores them; clamped
// tail rows are loaded-but-never-stored (their garbage is discarded).
__global__ __launch_bounds__(256) void k_gemm(const unsigned short* __restrict__ xb,
                                              const unsigned short* __restrict__ t1h,
                                              const float* __restrict__ w,
                                              const float* __restrict__ bias,
                                              float* out) {
  __shared__ unsigned short bp[6 * 4 * 64 * 8];  // 24KB packed B fragments
  const int t = threadIdx.x;
  // ---- pack combined weights into B-fragment order ----
  for (int idx = t; idx < 1536; idx += 256) {
    int kt = idx >> 8;                 // ktile 0..5
    int rem = idx & 255;
    int c = rem >> 6;                  // coltile 0..3
    int l = rem & 63;                  // frag lane
    int ch = kt >> 1;                  // channel 0..2
    int kbase = (kt & 1) * 32 + (l >> 4) * 8;
    int n = c * 16 + (l & 15);
    unsigned short* dst = &bp[idx * 8];
#pragma unroll
    for (int j = 0; j < 8; ++j) {
      int k = kbase + j;
      float v;
      if (ch == 0)      v = w[k * 64 + n] - w[8192 + k * 64 + n];
      else if (ch == 1) v = w[4096 + k * 64 + n];
      else              v = 2.0f * w[8192 + k * 64 + n];
      dst[j] = f2bf(v);
    }
  }
  __syncthreads();

  const int wid = t >> 6;
  const int lane = t & 63;
  const size_t base = (size_t)blockIdx.x * 64 + (size_t)wid * 16;  // wave's rows
  const int arow = lane & 15;
  const int ko = (lane >> 4) * 8;
  size_t row = base + arow;
  if (row > (size_t)(BN_ROWS - 1)) row = BN_ROWS - 1;  // clamped loads only

  // ---- A fragment loads (8 independent 16B loads, issued together) ----
  const unsigned short* xp = xb + row * 64 + ko;
  const unsigned short* tp = t1h + row * 64 + ko;
  const float* zp = out + row * 64 + ko;
  short8 ax0 = *(const short8*)(xp);
  short8 ax1 = *(const short8*)(xp + 32);
  short8 at0 = *(const short8*)(tp);
  short8 at1 = *(const short8*)(tp + 32);
  float4 z00 = *(const float4*)(zp);
  float4 z01 = *(const float4*)(zp + 4);
  float4 z10 = *(const float4*)(zp + 32);
  float4 z11 = *(const float4*)(zp + 36);
  short8 az0, az1;
  az0[0] = (short)f2bf(z00.x); az0[1] = (short)f2bf(z00.y);
  az0[2] = (short)f2bf(z00.z); az0[3] = (short)f2bf(z00.w);
  az0[4] = (short)f2bf(z01.x); az0[5] = (short)f2bf(z01.y);
  az0[6] = (short)f2bf(z01.z); az0[7] = (short)f2bf(z01.w);
  az1[0] = (short)f2bf(z10.x); az1[1] = (short)f2bf(z10.y);
  az1[2] = (short)f2bf(z10.z); az1[3] = (short)f2bf(z10.w);
  az1[4] = (short)f2bf(z11.x); az1[5] = (short)f2bf(z11.y);
  az1[6] = (short)f2bf(z11.z); az1[7] = (short)f2bf(z11.w);

  const int col = lane & 15;
  const int rgrp = lane >> 4;          // C/D row group: rows rgrp*4 + j

#pragma unroll
  for (int c = 0; c < 4; ++c) {
    const unsigned short* bb = &bp[(size_t)c * 64 * 8];
    short8 b0 = *(const short8*)(bb + (0 * 4 * 64 + lane) * 8);
    short8 b1 = *(const short8*)(bb + (1 * 4 * 64 + lane) * 8);
    short8 b2 = *(const short8*)(bb + (2 * 4 * 64 + lane) * 8);
    short8 b3 = *(const short8*)(bb + (3 * 4 * 64 + lane) * 8);
    short8 b4 = *(const short8*)(bb + (4 * 4 * 64 + lane) * 8);
    short8 b5 = *(const short8*)(bb + (5 * 4 * 64 + lane) * 8);
    f32x4 acc = {0.f, 0.f, 0.f, 0.f};
    acc = __builtin_amdgcn_mfma_f32_16x16x32_bf16(ax0, b0, acc, 0, 0, 0);
    acc = __builtin_amdgcn_mfma_f32_16x16x32_bf16(ax1, b1, acc, 0, 0, 0);
    acc = __builtin_amdgcn_mfma_f32_16x16x32_bf16(at0, b2, acc, 0, 0, 0);
    acc = __builtin_amdgcn_mfma_f32_16x16x32_bf16(at1, b3, acc, 0, 0, 0);
    acc = __builtin_amdgcn_mfma_f32_16x16x32_bf16(az0, b4, acc, 0, 0, 0);
    acc = __builtin_amdgcn_mfma_f32_16x16x32_bf16(az1, b5, acc, 0, 0, 0);
    const float bcol = bias[c * 16 + col];
#pragma unroll
    for (int j = 0; j < 4; ++j) {
      size_t r = base + (size_t)(rgrp * 4 + j);
      if (r < BN_ROWS) out[r * 64 + c * 16 + col] = acc[j] + bcol;
    }
  }
}

extern "C" void kernel_launch(void* const* d_in, const int* in_sizes, int n_in,
                              void* d_out, int out_size, void* d_ws, size_t ws_size,
                              hipStream_t stream) {
  const float* x = (const float*)d_in[0];
  const int* ei = (const int*)d_in[1];        // [2, E] int32
  const float* ew = (const float*)d_in[2];
  const float* w = (const float*)d_in[3];     // [3,64,64]
  const float* bias = (const float*)d_in[4];  // [64]
  float* out = (float*)d_out;

  // workspace layout (4-byte units)
  int* ws32 = (int*)d_ws;
  const size_t NA = 50048;  // padded N (divisible by 16 -> keeps 16B alignment)
  int* deg = ws32;                          // [0..N) degrees, [N] = counter
  int* counter = deg + N_NODES;
  int* cursor = ws32 + NA;
  float* dis = (float*)(cursor + NA);
  int* rowptr = (int*)(dis + NA);
  int2* ccv = (int2*)(rowptr + NA);                       // 2*E ints
  unsigned short* xb = (unsigned short*)(rowptr + NA + 2 * N_EDGES);   // BN_ROWS*64 bf16
  unsigned short* t1h = xb + (size_t)BN_ROWS * N_C;                    // BN_ROWS*64 bf16
  const size_t NEED = ((size_t)(4 * NA + 2 * N_EDGES) + (size_t)BN_ROWS * N_C) * 4;
  if (ws_size < NEED) return;  // clean fail instead of corruption

  hipMemsetAsync(deg, 0, (N_NODES + 1) * sizeof(int), stream);  // deg + counter
  k_cvt<<<(BN_ROWS * 16 + 255) / 256, 256, 0, stream>>>(x, xb);
  k_deg<<<(N_EDGES + 255) / 256, 256, 0, stream>>>(ei, deg);
  k_offsets<<<(N_NODES + 255) / 256, 256, 0, stream>>>(deg, counter, rowptr, cursor, dis);
  k_fill<<<(N_EDGES + 255) / 256, 256, 0, stream>>>(ei, ew, dis, cursor, ccv);
  // Tx1 = L x   (bf16 out, both batches per wave)
  k_spmm<1><<<(N_NODES * 64 + 255) / 256, 256, 0, stream>>>(xb, t1h, rowptr, deg, ccv);
  // Z = L Tx1   (fp32, into d_out, both batches per wave)
  k_spmm<0><<<(N_NODES * 64 + 255) / 256, 256, 0, stream>>>(t1h, out, rowptr, deg, ccv);
  // out = [x|Tx1|Z] @ [W0-W2; W1; 2W2] + bias  (MFMA, in-place over Z)
  k_gemm<<<(BN_ROWS + 63) / 64, 256, 0, stream>>>(xb, t1h, w, bias, out);
}